// Round 7
// baseline (299.471 us; speedup 1.0000x reference)
//
#include <hip/hip_runtime.h>
#include <cstdint>

#if __has_builtin(__builtin_amdgcn_exp2f)
#define EXP2F(x) __builtin_amdgcn_exp2f(x)
#else
#define EXP2F(x) exp2f(x)
#endif

typedef _Float16 half8 __attribute__((ext_vector_type(8)));
typedef float    f32x4 __attribute__((ext_vector_type(4)));

// x: (4,1024,64,512) f32; u = x[...,0:256], v = x[...,256:512]
// d = vd*16 + s (head s = d&15); head params hb = s*1024 + w
// score(m,n) = ax*dx + ay*dy - 0.5*(dx^2+dy^2); dx = (n&7)-(m&7), dy = (m>>3)-(n>>3)
// mixed[m,vd,s] = softmax_n(score).Us[n,vd,s]; out = (mixed + bias[w,m]) * v
//
// Round 6: persistent WGs + raw-barrier pipeline.
//  grid = 1024, each WG does blocks bw = wg + it*1024 (same w for all it ->
//  head-param setup hoisted out of the loop). All barriers are raw s_barrier
//  preceded by s_waitcnt lgkmcnt(0) ONLY — vmcnt is never drained, so global
//  loads stay in flight across phase boundaries (T3/T4 mechanism; HIP
//  __syncthreads would drain vmcnt(0) and kill the pipeline).
//  Cross-block prefetch: next block's u (8x dwordx4) issued right after this
//  block's first barrier; v row-pairs issued one quarter ahead of use.
//  LDS 48 KB: Us f16 [s][vd][qb][j] (32 KB, qb = q^(vd&7)), Qm f32 [16][256]
//  quarter buffer (16 KB, col ^ ((m&7)<<2)).

#define BARRIER() do {                                        \
    asm volatile("s_waitcnt lgkmcnt(0)" ::: "memory");        \
    __builtin_amdgcn_s_barrier();                             \
} while (0)

__global__ __launch_bounds__(512, 4) void sgating_kernel(
    const float* __restrict__ x,
    const float* __restrict__ norm_w,
    const float* __restrict__ norm_b,
    const float* __restrict__ centers,
    const float* __restrict__ spreads,
    const float* __restrict__ tbias,
    float* __restrict__ out,
    int nit)
{
    __shared__ __align__(16) float smem[12288];   // 48 KB: Us 32K + Qm 16K
    _Float16* Us = (_Float16*)smem;
    float*    Qm = smem + 8192;

    const int t     = threadIdx.x;
    const int wv    = t >> 6;
    const int lane  = t & 63;
    const int wg    = blockIdx.x;
    const int w_idx = wg & 1023;

    const int m16 = lane & 15;
    const int g   = lane >> 4;
    const float LOG2E = 1.4426950408889634f;
    const float C2    = 0.72134752044448f;   // 0.5*log2(e)
    const float mx  = (float)(m16 & 7);
    const float myb = (float)(m16 >> 3);
    const int sA = wv, sB = wv + 8;

    // ---------------- per-WG setup (w-invariant across it) ----------------
    const float4 w4 = *(const float4*)(norm_w + lane * 4);
    const float4 b4 = *(const float4*)(norm_b + lane * 4);

    float bias4[4];
#pragma unroll
    for (int nt = 0; nt < 4; ++nt)
        bias4[nt] = tbias[w_idx * 64 + nt * 16 + m16];

    float    exfA[2], exfB[2];
    _Float16 exhA[2], exhB[2];
    half8 EYA_[2], EYB_[2];     // 14-entry f16 ey tables, i -> dy = i-7+myb
    {
        const int hbA = (sA << 10) | w_idx;
        const int hbB = (sB << 10) | w_idx;
        float aq = spreads[hbA]; aq *= aq;
        const float axlA = aq * centers[2*hbA]     * LOG2E;
        const float aylA = aq * centers[2*hbA + 1] * LOG2E;
        aq = spreads[hbB]; aq *= aq;
        const float axlB = aq * centers[2*hbB]     * LOG2E;
        const float aylB = aq * centers[2*hbB + 1] * LOG2E;
#pragma unroll
        for (int kt = 0; kt < 2; ++kt) {
            const float dx = (float)(g + 4*kt) - mx;
            const float eA = EXP2F(dx * fmaf(-C2, dx, axlA));
            const float eB = EXP2F(dx * fmaf(-C2, dx, axlB));
            exfA[kt] = eA; exhA[kt] = (_Float16)eA;
            exfB[kt] = eB; exhB[kt] = (_Float16)eB;
        }
#pragma unroll
        for (int i = 0; i < 16; ++i) {
            const float dy = (float)(i - 7) + myb;
            const _Float16 eA = (i < 14) ? (_Float16)EXP2F(dy * fmaf(-C2, dy, aylA)) : (_Float16)0.f;
            const _Float16 eB = (i < 14) ? (_Float16)EXP2F(dy * fmaf(-C2, dy, aylB)) : (_Float16)0.f;
            if (i < 8) { EYA_[0][i] = eA; EYB_[0][i] = eB; }
            else       { EYA_[1][i-8] = eA; EYB_[1][i-8] = eB; }
        }
    }

#define EYAT(I) ((I) < 8 ? EYA_[0][(I)] : EYA_[1][(I)-8])
#define EYBT(I) ((I) < 8 ? EYB_[0][(I)] : EYB_[1][(I)-8])

#define CQ(NT, vOutA, vOutB) do {                                              \
    f32x4 aA = (f32x4){0.f,0.f,0.f,0.f};                                       \
    f32x4 aB = (f32x4){0.f,0.f,0.f,0.f};                                       \
    half8 eyA8, eyB8;                                                          \
    float syA = 0.f, syB = 0.f;                                                \
    _Pragma("unroll") for (int j = 0; j < 8; ++j) {                            \
        const _Float16 ea = EYAT(2*(NT)+7-j);                                  \
        const _Float16 eb = EYBT(2*(NT)+7-j);                                  \
        eyA8[j] = ea; eyB8[j] = eb;                                            \
        syA += (float)ea; syB += (float)eb;                                    \
    }                                                                          \
    _Pragma("unroll") for (int kt = 0; kt < 2; ++kt) {                         \
        const int qb = (g + 4*kt) ^ (m16 & 7);                                 \
        const half8 uA = *(const half8*)(Us + (sA<<10) + (m16<<6) + (qb<<3));  \
        const half8 uB = *(const half8*)(Us + (sB<<10) + (m16<<6) + (qb<<3));  \
        half8 wA, wB;                                                          \
        _Pragma("unroll") for (int j = 0; j < 8; ++j) {                        \
            wA[j] = eyA8[j] * exhA[kt];                                        \
            wB[j] = eyB8[j] * exhB[kt];                                        \
        }                                                                      \
        aA = __builtin_amdgcn_mfma_f32_16x16x32_f16(uA, wA, aA, 0, 0, 0);      \
        aB = __builtin_amdgcn_mfma_f32_16x16x32_f16(uB, wB, aB, 0, 0, 0);      \
    }                                                                          \
    float rA = (exfA[0] + exfA[1]) * syA;                                      \
    rA += __shfl_xor(rA, 16); rA += __shfl_xor(rA, 32);                        \
    float rB = (exfB[0] + exfB[1]) * syB;                                      \
    rB += __shfl_xor(rB, 16); rB += __shfl_xor(rB, 32);                        \
    const float iA = 1.0f / rA;                                                \
    const float iB = 1.0f / rB;                                                \
    const float bm = bias4[(NT)];                                              \
    _Pragma("unroll") for (int j = 0; j < 4; ++j) {                            \
        vOutA[j] = aA[j]*iA + bm;                                              \
        vOutB[j] = aB[j]*iB + bm;                                              \
    }                                                                          \
} while (0)

#define WRITEQ(vA_, vB_) do {                                                  \
    const int swz = (m16 & 7) << 2;                                            \
    *(f32x4*)(Qm + (m16<<8) + ((sA*16 + g*4) ^ swz)) = vA_;                    \
    *(f32x4*)(Qm + (m16<<8) + ((sB*16 + g*4) ^ swz)) = vB_;                    \
} while (0)

#define VLOAD(NT, V0, V1) do {                                                 \
    V0 = *(const f32x4*)(x + xbase + (size_t)(16*(NT)+wv)*512 + 256 + lane*4); \
    V1 = *(const f32x4*)(x + xbase + (size_t)(16*(NT)+8+wv)*512 + 256 + lane*4);\
} while (0)

#define EPIK(NT, K, VH) do {                                                   \
    const int mr  = wv + 8*(K);                                                \
    const int m   = (NT)*16 + mr;                                              \
    const int c4  = lane * 4;                                                  \
    const int vd  = c4 >> 4;                                                   \
    const int s0  = c4 & 15;                                                   \
    const int sw2 = (m & 7) << 2;                                              \
    f32x4 mxv;                                                                 \
    mxv[0] = Qm[(mr<<8) + ((((s0+0)<<4)+vd) ^ sw2)];                           \
    mxv[1] = Qm[(mr<<8) + ((((s0+1)<<4)+vd) ^ sw2)];                           \
    mxv[2] = Qm[(mr<<8) + ((((s0+2)<<4)+vd) ^ sw2)];                           \
    mxv[3] = Qm[(mr<<8) + ((((s0+3)<<4)+vd) ^ sw2)];                           \
    f32x4 o;                                                                   \
    o[0] = mxv[0] * (VH)[0]; o[1] = mxv[1] * (VH)[1];                          \
    o[2] = mxv[2] * (VH)[2]; o[3] = mxv[3] * (VH)[3];                          \
    __builtin_nontemporal_store(o, (f32x4*)(out + obase + m*256 + c4));        \
} while (0)

    // ---------------- prologue: load u for first block ----------------
    f32x4 un[8];
    {
        const size_t xb0 = (size_t)wg * (64 * 512);
#pragma unroll
        for (int r = 0; r < 8; ++r)
            un[r] = *(const f32x4*)(x + xb0 + (size_t)(r*8 + wv)*512 + lane*4);
    }

    for (int it = 0; it < nit; ++it) {
        const int bw = wg + (it << 10);
        const size_t xbase = (size_t)bw * (64 * 512);
        const size_t obase = (size_t)bw * (64 * 256);

        // ---------------- Phase 1: LayerNorm(un) -> Us ----------------
        {
            half8 uar[4];
#pragma unroll
            for (int r = 0; r < 8; ++r) {
                const f32x4 u = un[r];
                float s  = u[0] + u[1] + u[2] + u[3];
                float sq = u[0]*u[0] + u[1]*u[1] + u[2]*u[2] + u[3]*u[3];
#pragma unroll
                for (int off = 1; off < 64; off <<= 1) {
                    s  += __shfl_xor(s, off);
                    sq += __shfl_xor(sq, off);
                }
                const float mean = s * (1.0f/256.0f);
                const float var  = sq * (1.0f/256.0f) - mean*mean;
                const float rstd = rsqrtf(var + 1e-5f);
                uar[0][r] = (_Float16)((u[0] - mean)*rstd*w4.x + b4.x);
                uar[1][r] = (_Float16)((u[1] - mean)*rstd*w4.y + b4.y);
                uar[2][r] = (_Float16)((u[2] - mean)*rstd*w4.z + b4.z);
                uar[3][r] = (_Float16)((u[3] - mean)*rstd*w4.w + b4.w);
            }
#pragma unroll
            for (int j = 0; j < 4; ++j) {
                const int d  = lane * 4 + j;
                const int s  = d & 15;
                const int vd = d >> 4;
                const int qb = wv ^ (vd & 7);
                *(half8*)(Us + (s << 10) + (vd << 6) + (qb << 3)) = uar[j];
            }
        }

        f32x4 v0, v1, v2, v3, v4, v5, v6, v7;
        VLOAD(0, v0, v1);                       // issue early; used in EPIK(0)
        BARRIER();                              // Us visible (lgkm only)

        // prefetch next block's u — stays in flight across raw barriers
        if (it + 1 < nit) {
            const size_t xbn = (size_t)(bw + 1024) * (64 * 512);
#pragma unroll
            for (int r = 0; r < 8; ++r)
                un[r] = *(const f32x4*)(x + xbn + (size_t)(r*8 + wv)*512 + lane*4);
        }

        f32x4 cA, cB, nA2, nB2;
        CQ(0, cA, cB);
        WRITEQ(cA, cB);
        BARRIER();

        VLOAD(1, v2, v3);
        CQ(1, nA2, nB2);
        EPIK(0, 0, v0); EPIK(0, 1, v1);
        BARRIER();
        WRITEQ(nA2, nB2);
        BARRIER();

        VLOAD(2, v4, v5);
        CQ(2, cA, cB);
        EPIK(1, 0, v2); EPIK(1, 1, v3);
        BARRIER();
        WRITEQ(cA, cB);
        BARRIER();

        VLOAD(3, v6, v7);
        CQ(3, nA2, nB2);
        EPIK(2, 0, v4); EPIK(2, 1, v5);
        BARRIER();
        WRITEQ(nA2, nB2);
        BARRIER();

        EPIK(3, 0, v6); EPIK(3, 1, v7);
        // no end-of-block barrier needed: next block's first BARRIER (after
        // LN/Us-writes, which touch the Us region only) separates this
        // block's Qm reads from the next block's Qm writes.
    }
}

extern "C" void kernel_launch(void* const* d_in, const int* in_sizes, int n_in,
                              void* d_out, int out_size, void* d_ws, size_t ws_size,
                              hipStream_t stream) {
    const float* x       = (const float*)d_in[0];
    const float* norm_w  = (const float*)d_in[1];
    const float* norm_b  = (const float*)d_in[2];
    const float* centers = (const float*)d_in[3];
    const float* spreads = (const float*)d_in[4];
    const float* tbias   = (const float*)d_in[5];
    float* out = (float*)d_out;

    const int nbw = in_sizes[0] / (64 * 512);   // 4096 expected
    int grid, nit;
    if (nbw % 1024 == 0) { grid = 1024; nit = nbw / 1024; }
    else                 { grid = nbw;  nit = 1; }
    hipLaunchKernelGGL(sgating_kernel, dim3(grid), dim3(512), 0, stream,
                       x, norm_w, norm_b, centers, spreads, tbias, out, nit);
}

// Round 8
// 156.358 us; speedup vs baseline: 1.9153x; 1.9153x over previous
//
#include <hip/hip_runtime.h>
#include <cstdint>

#if __has_builtin(__builtin_amdgcn_exp2f)
#define EXP2F(x) __builtin_amdgcn_exp2f(x)
#else
#define EXP2F(x) exp2f(x)
#endif

typedef _Float16 half8 __attribute__((ext_vector_type(8)));
typedef _Float16 half4 __attribute__((ext_vector_type(4)));
typedef float    f32x4 __attribute__((ext_vector_type(4)));

// x: (4,1024,64,512) f32; u = x[...,0:256], v = x[...,256:512]
// d = vd*16 + s (head s = d&15); head params hb = s*1024 + w
// score(m,n) = ax*dx + ay*dy - 0.5*(dx^2+dy^2); dx = (n&7)-(m&7), dy = (m>>3)-(n>>3)
// mixed[m,vd,s] = softmax_n(score).Us[n,vd,s]; out = (mixed + bias[w,m]) * v
//
// Round 7 = round 5b EXACTLY, except: all __syncthreads() replaced by raw
// s_barrier + s_waitcnt lgkmcnt(0) (T4). __syncthreads drains vmcnt(0),
// forcing every barrier to wait on outstanding NT-store acks; lgkm-only
// barriers let stores stay in flight across phase boundaries. All LDS
// handoffs (Us w->r, Qm w->r, Qm r->w) are ordered by lgkmcnt(0); global
// stores are never read back; compiler handles load-use vmcnt by data dep.

#define BARRIER() do {                                        \
    asm volatile("s_waitcnt lgkmcnt(0)" ::: "memory");        \
    __builtin_amdgcn_s_barrier();                             \
} while (0)

__global__ __launch_bounds__(512, 4) void sgating_kernel(
    const float* __restrict__ x,
    const float* __restrict__ norm_w,
    const float* __restrict__ norm_b,
    const float* __restrict__ centers,
    const float* __restrict__ spreads,
    const float* __restrict__ tbias,
    float* __restrict__ out)
{
    __shared__ __align__(16) float smem[12288];   // 48 KB: Us 32K + Qm 16K
    _Float16* Us = (_Float16*)smem;
    float*    Qm = smem + 8192;

    const int t     = threadIdx.x;
    const int wv    = t >> 6;
    const int lane  = t & 63;
    const int bw    = blockIdx.x;       // b*1024 + w
    const int w_idx = bw & 1023;
    const size_t xbase = (size_t)bw * (64 * 512);
    const size_t obase = (size_t)bw * (64 * 256);

    half4 vreg[8];                      // v rows r*8+wv, elems lane*4..+3 (f16)

    // ---------------- Phase 1: single-pass load + LayerNorm(u) -> Us ----------------
    {
        const float4 w4 = *(const float4*)(norm_w + lane * 4);
        const float4 b4 = *(const float4*)(norm_b + lane * 4);
        half8 uar[4];
#pragma unroll
        for (int r = 0; r < 8; ++r) {
            const int n = r * 8 + wv;
            const float* rowp = x + xbase + (size_t)n * 512 + lane * 4;
            const float4 u  = *(const float4*)(rowp);
            const float4 vv = *(const float4*)(rowp + 256);
            vreg[r][0] = (_Float16)vv.x; vreg[r][1] = (_Float16)vv.y;
            vreg[r][2] = (_Float16)vv.z; vreg[r][3] = (_Float16)vv.w;
            float s  = u.x + u.y + u.z + u.w;
            float sq = u.x*u.x + u.y*u.y + u.z*u.z + u.w*u.w;
#pragma unroll
            for (int off = 1; off < 64; off <<= 1) {
                s  += __shfl_xor(s, off);
                sq += __shfl_xor(sq, off);
            }
            const float mean = s * (1.0f/256.0f);
            const float var  = sq * (1.0f/256.0f) - mean*mean;
            const float rstd = rsqrtf(var + 1e-5f);
            uar[0][r] = (_Float16)((u.x - mean)*rstd*w4.x + b4.x);
            uar[1][r] = (_Float16)((u.y - mean)*rstd*w4.y + b4.y);
            uar[2][r] = (_Float16)((u.z - mean)*rstd*w4.z + b4.z);
            uar[3][r] = (_Float16)((u.w - mean)*rstd*w4.w + b4.w);
        }
        // uar[j][r] = value at n = r*8+wv (q = wv, j-slot = r) -> contiguous b128
#pragma unroll
        for (int j = 0; j < 4; ++j) {
            const int d  = lane * 4 + j;
            const int s  = d & 15;
            const int vd = d >> 4;
            const int qb = wv ^ (vd & 7);
            *(half8*)(Us + (s << 10) + (vd << 6) + (qb << 3)) = uar[j];
        }
    }
    BARRIER();

    // ---------------- Phase 2 setup ----------------
    const int m16 = lane & 15;
    const int g   = lane >> 4;
    const float LOG2E = 1.4426950408889634f;
    const float C2    = 0.72134752044448f;   // 0.5*log2(e)
    const float mx  = (float)(m16 & 7);
    const float myb = (float)(m16 >> 3);
    const int sA = wv, sB = wv + 8;

    float bias4[4];
#pragma unroll
    for (int nt = 0; nt < 4; ++nt)
        bias4[nt] = tbias[w_idx * 64 + nt * 16 + m16];

    float    exfA[2], exfB[2];
    _Float16 exhA[2], exhB[2];
    half8 EYA_[2], EYB_[2];     // 14-entry f16 ey tables, i -> dy = i-7+myb
    {
        const int hbA = (sA << 10) | w_idx;
        const int hbB = (sB << 10) | w_idx;
        float aq = spreads[hbA]; aq *= aq;
        const float axlA = aq * centers[2*hbA]     * LOG2E;
        const float aylA = aq * centers[2*hbA + 1] * LOG2E;
        aq = spreads[hbB]; aq *= aq;
        const float axlB = aq * centers[2*hbB]     * LOG2E;
        const float aylB = aq * centers[2*hbB + 1] * LOG2E;
#pragma unroll
        for (int kt = 0; kt < 2; ++kt) {
            const float dx = (float)(g + 4*kt) - mx;
            const float eA = EXP2F(dx * fmaf(-C2, dx, axlA));
            const float eB = EXP2F(dx * fmaf(-C2, dx, axlB));
            exfA[kt] = eA; exhA[kt] = (_Float16)eA;
            exfB[kt] = eB; exhB[kt] = (_Float16)eB;
        }
#pragma unroll
        for (int i = 0; i < 16; ++i) {
            const float dy = (float)(i - 7) + myb;
            const _Float16 eA = (i < 14) ? (_Float16)EXP2F(dy * fmaf(-C2, dy, aylA)) : (_Float16)0.f;
            const _Float16 eB = (i < 14) ? (_Float16)EXP2F(dy * fmaf(-C2, dy, aylB)) : (_Float16)0.f;
            if (i < 8) { EYA_[0][i] = eA; EYB_[0][i] = eB; }
            else       { EYA_[1][i-8] = eA; EYB_[1][i-8] = eB; }
        }
    }

#define EYAT(I) ((I) < 8 ? EYA_[0][(I)] : EYA_[1][(I)-8])
#define EYBT(I) ((I) < 8 ? EYB_[0][(I)] : EYB_[1][(I)-8])

#define CQ(NT, vOutA, vOutB) do {                                              \
    f32x4 aA = (f32x4){0.f,0.f,0.f,0.f};                                       \
    f32x4 aB = (f32x4){0.f,0.f,0.f,0.f};                                       \
    half8 eyA8, eyB8;                                                          \
    float syA = 0.f, syB = 0.f;                                                \
    _Pragma("unroll") for (int j = 0; j < 8; ++j) {                            \
        const _Float16 ea = EYAT(2*(NT)+7-j);                                  \
        const _Float16 eb = EYBT(2*(NT)+7-j);                                  \
        eyA8[j] = ea; eyB8[j] = eb;                                            \
        syA += (float)ea; syB += (float)eb;                                    \
    }                                                                          \
    _Pragma("unroll") for (int kt = 0; kt < 2; ++kt) {                         \
        const int qb = (g + 4*kt) ^ (m16 & 7);                                 \
        const half8 uA = *(const half8*)(Us + (sA<<10) + (m16<<6) + (qb<<3));  \
        const half8 uB = *(const half8*)(Us + (sB<<10) + (m16<<6) + (qb<<3));  \
        half8 wA, wB;                                                          \
        _Pragma("unroll") for (int j = 0; j < 8; ++j) {                        \
            wA[j] = eyA8[j] * exhA[kt];                                        \
            wB[j] = eyB8[j] * exhB[kt];                                        \
        }                                                                      \
        aA = __builtin_amdgcn_mfma_f32_16x16x32_f16(uA, wA, aA, 0, 0, 0);      \
        aB = __builtin_amdgcn_mfma_f32_16x16x32_f16(uB, wB, aB, 0, 0, 0);      \
    }                                                                          \
    float rA = (exfA[0] + exfA[1]) * syA;                                      \
    rA += __shfl_xor(rA, 16); rA += __shfl_xor(rA, 32);                        \
    float rB = (exfB[0] + exfB[1]) * syB;                                      \
    rB += __shfl_xor(rB, 16); rB += __shfl_xor(rB, 32);                        \
    const float iA = 1.0f / rA;                                                \
    const float iB = 1.0f / rB;                                                \
    const float bm = bias4[(NT)];                                              \
    _Pragma("unroll") for (int j = 0; j < 4; ++j) {                            \
        vOutA[j] = aA[j]*iA + bm;                                              \
        vOutB[j] = aB[j]*iB + bm;                                              \
    }                                                                          \
} while (0)

#define WRITEQ(vA_, vB_) do {                                                  \
    const int swz = (m16 & 7) << 2;                                            \
    *(f32x4*)(Qm + (m16<<8) + ((sA*16 + g*4) ^ swz)) = vA_;                    \
    *(f32x4*)(Qm + (m16<<8) + ((sB*16 + g*4) ^ swz)) = vB_;                    \
} while (0)

#define EPIK(NT, K) do {                                                       \
    const int mr  = wv + 8*(K);                                                \
    const int m   = (NT)*16 + mr;                                              \
    const int c4  = lane * 4;                                                  \
    const int vd  = c4 >> 4;                                                   \
    const int s0  = c4 & 15;                                                   \
    const int sw2 = (m & 7) << 2;                                              \
    f32x4 mxv;                                                                 \
    mxv[0] = Qm[(mr<<8) + ((((s0+0)<<4)+vd) ^ sw2)];                           \
    mxv[1] = Qm[(mr<<8) + ((((s0+1)<<4)+vd) ^ sw2)];                           \
    mxv[2] = Qm[(mr<<8) + ((((s0+2)<<4)+vd) ^ sw2)];                           \
    mxv[3] = Qm[(mr<<8) + ((((s0+3)<<4)+vd) ^ sw2)];                           \
    const half4 vh = vreg[2*(NT)+(K)];                                         \
    f32x4 o;                                                                   \
    o[0] = mxv[0] * (float)vh[0]; o[1] = mxv[1] * (float)vh[1];                \
    o[2] = mxv[2] * (float)vh[2]; o[3] = mxv[3] * (float)vh[3];                \
    __builtin_nontemporal_store(o, (f32x4*)(out + obase + m*256 + c4));        \
} while (0)

    // ---------------- Phase 2/3: quarter-pipelined (no global loads) ----------------
    f32x4 cA, cB, nA2, nB2;
    CQ(0, cA, cB);

    WRITEQ(cA, cB);
    BARRIER();
    CQ(1, nA2, nB2);
    EPIK(0, 0); EPIK(0, 1);
    BARRIER();
    cA = nA2; cB = nB2;

    WRITEQ(cA, cB);
    BARRIER();
    CQ(2, nA2, nB2);
    EPIK(1, 0); EPIK(1, 1);
    BARRIER();
    cA = nA2; cB = nB2;

    WRITEQ(cA, cB);
    BARRIER();
    CQ(3, nA2, nB2);
    EPIK(2, 0); EPIK(2, 1);
    BARRIER();
    cA = nA2; cB = nB2;

    WRITEQ(cA, cB);
    BARRIER();
    EPIK(3, 0); EPIK(3, 1);
}

extern "C" void kernel_launch(void* const* d_in, const int* in_sizes, int n_in,
                              void* d_out, int out_size, void* d_ws, size_t ws_size,
                              hipStream_t stream) {
    const float* x       = (const float*)d_in[0];
    const float* norm_w  = (const float*)d_in[1];
    const float* norm_b  = (const float*)d_in[2];
    const float* centers = (const float*)d_in[3];
    const float* spreads = (const float*)d_in[4];
    const float* tbias   = (const float*)d_in[5];
    float* out = (float*)d_out;

    const int nbw = in_sizes[0] / (64 * 512);   // 4096
    hipLaunchKernelGGL(sgating_kernel, dim3(nbw), dim3(512), 0, stream,
                       x, norm_w, norm_b, centers, spreads, tbias, out);
}